// Round 10
// baseline (791.696 us; speedup 1.0000x reference)
//
#include <hip/hip_runtime.h>
#include <hip/hip_bf16.h>
#include <math.h>

typedef __attribute__((ext_vector_type(4))) int intx4;   // 16 i8 or 4 i32

__device__ __forceinline__ void gload_lds16(const void* g, void* l) {
  __builtin_amdgcn_global_load_lds((__attribute__((address_space(1))) void*)g,
                                   (__attribute__((address_space(3))) void*)l,
                                   16, 0, 0);
}

__device__ __forceinline__ int pack4_i8(float a, float b, float c, float d) {
  return ((int)a & 255) | (((int)b & 255) << 8) | (((int)c & 255) << 16) | (((int)d & 255) << 24);
}

// ---------------------------------------------------------------------------
// Per-row symmetric int8 fake-quant (unchanged from round 9, validated).
// ---------------------------------------------------------------------------
template<int NITER>
__global__ void quant_rows_i8_kernel(const float* __restrict__ src,
                                     signed char* __restrict__ dst,
                                     float* __restrict__ scales,
                                     int C) {
  const int row = blockIdx.x;
  const int t = threadIdx.x;
  const float4* s4 = (const float4*)(src + (size_t)row * C);
  float4 v[NITER];
  float amax = 0.0f;
#pragma unroll
  for (int i = 0; i < NITER; ++i) {
    v[i] = s4[t + (i << 8)];
    amax = fmaxf(amax, fmaxf(fmaxf(fabsf(v[i].x), fabsf(v[i].y)),
                             fmaxf(fabsf(v[i].z), fabsf(v[i].w))));
  }
#pragma unroll
  for (int off = 32; off > 0; off >>= 1)
    amax = fmaxf(amax, __shfl_xor(amax, off));
  __shared__ float red[4];
  if ((t & 63) == 0) red[t >> 6] = amax;
  __syncthreads();
  if (t == 0) {
    float m = fmaxf(fmaxf(red[0], red[1]), fmaxf(red[2], red[3]));
    float s = fmaxf(m * (1.0f / 127.0f), 1e-8f);
    red[0] = s;
    scales[row] = s;
  }
  __syncthreads();
  const float scale = red[0];
  int* o4 = (int*)(dst + (size_t)row * C);
#pragma unroll
  for (int i = 0; i < NITER; ++i) {
    const float q0 = fminf(fmaxf(rintf(v[i].x / scale), -127.0f), 127.0f);
    const float q1 = fminf(fmaxf(rintf(v[i].y / scale), -127.0f), 127.0f);
    const float q2 = fminf(fmaxf(rintf(v[i].z / scale), -127.0f), 127.0f);
    const float q3 = fminf(fmaxf(rintf(v[i].w / scale), -127.0f), 127.0f);
    o4[t + (i << 8)] = pack4_i8(q0, q1, q2, q3);
  }
}

// ---------------------------------------------------------------------------
// 256x256 i8 GEMM, 4-phase counted-vmcnt schedule (T2+T3+T4+T5 port).
//
// LDS (131072 B, dbuf): buf P at P*65536:
//   A planes: [ks=0: 256r x 64B @0] [ks=1 @16384]; B planes @32768 likewise.
// Stage unit = one plane = 1024 x 16B chunks, 2 gload_lds/thread (512 thr).
//   chunk c -> r=c>>2, lds slot=c&3; SOURCE col-slot = (c&3) ^ ((r>>1)&3)
//   (rule #21 both-sides involution; reads apply the same XOR).
// Bank math: 16-lane frag read -> banks 16(r&1)+4(slot^((r>>1)&3)) = 8
//   positions x 2 lanes = 2-way = free (m136; round-9 measured-0 class).
// Waves: 8 = 2M x 4N; wave tile 128x64; per K-tile 64 MFMA in 4 phases of 16.
// Counted pipeline (per-thread vmcnt trace, steady state, 4 loads in flight):
//   ph0: rd A.ks0(8) B.j01.ks0 | stage next A.ks0 | bar | 16 mfma | bar
//   ph1: rd B.j23.ks0          | stage next B.ks0 | bar | 16 mfma | vmcnt(4) bar
//   ph2: rd A.ks1(8) B.j01.ks1 | stage next A.ks1 | bar | 16 mfma | bar
//   ph3: rd B.j23.ks1          | stage next B.ks1 | bar | 16 mfma | vmcnt(4) bar
//   vmcnt(4) forces the pair needed 2 phases later, leaves newest 4 in flight.
//   Last tile: vmcnt(0) (nothing staged). Prologue: stage 4 planes, vmcnt(0), bar.
// MODE 0: out = acc*sa*sb.  MODE 1: g=out[..]; out = silu(g) * (acc*sa*sb).
// ---------------------------------------------------------------------------
#define SBAR() __builtin_amdgcn_s_barrier()
#define VMW(more) do { if (more) asm volatile("s_waitcnt vmcnt(4)" ::: "memory"); \
                       else      asm volatile("s_waitcnt vmcnt(0)" ::: "memory"); } while (0)

__device__ __forceinline__ void stage_plane(const signed char* __restrict__ mat,
                                            int rowbase, int K, int kcol,
                                            char* lds, int tid) {
#pragma unroll
  for (int u = 0; u < 2; ++u) {
    const int c = (u << 9) + tid;               // 0..1023
    const int r = c >> 2;                       // 0..255
    const int src = (c & 3) ^ ((r >> 1) & 3);   // pre-swizzled source slot
    gload_lds16(mat + (size_t)(rowbase + r) * K + (kcol + (src << 4)), lds + (c << 4));
  }
}

template<int MODE>
__global__ __launch_bounds__(512, 2)
void gemm8p_kernel(const signed char* __restrict__ A,
                   const signed char* __restrict__ B,
                   const float* __restrict__ sA,
                   const float* __restrict__ sB,
                   float* __restrict__ out,
                   int N, int K) {
  extern __shared__ __align__(16) char smem[];
  const int nTn = N >> 8;
  const int nwg = gridDim.x;
  const int bid = blockIdx.x;
  const int cpx = nwg >> 3;                     // grids are multiples of 8
  const int swz = (bid & 7) * cpx + (bid >> 3);
  const int tm = swz / nTn, tn = swz - tm * nTn;
  const int m0 = tm << 8, n0 = tn << 8;

  const int tid = threadIdx.x;
  const int lane = tid & 63;
  const int wid = tid >> 6;
  const int wr = wid >> 2, wc = wid & 3;        // 2M x 4N waves
  const int l15 = lane & 15, slq = lane >> 4;
  const int NT = K >> 7;

  const intx4 zero = {0, 0, 0, 0};
  intx4 acc[8][4];
#pragma unroll
  for (int i = 0; i < 8; ++i)
#pragma unroll
    for (int j = 0; j < 4; ++j) acc[i][j] = zero;

  auto rdA = [&](char* buf, int ks, int i) -> intx4 {
    const int r = (wr << 7) + (i << 4) + l15;
    return *(const intx4*)(buf + (ks << 14) + (r << 6) + ((slq ^ ((r >> 1) & 3)) << 4));
  };
  auto rdB = [&](char* buf, int ks, int j) -> intx4 {
    const int r = (wc << 6) + (j << 4) + l15;
    return *(const intx4*)(buf + 32768 + (ks << 14) + (r << 6) + ((slq ^ ((r >> 1) & 3)) << 4));
  };

  // prologue: stage tile 0 into buf0, full drain, barrier
  stage_plane(A, m0, K, 0,  smem,          tid);
  stage_plane(B, n0, K, 0,  smem + 32768,  tid);
  stage_plane(A, m0, K, 64, smem + 16384,  tid);
  stage_plane(B, n0, K, 64, smem + 49152,  tid);
  asm volatile("s_waitcnt vmcnt(0)" ::: "memory");
  SBAR();

  for (int t = 0; t < NT; ++t) {
    char* const bufc = smem + ((t & 1) << 16);
    char* const bufn = smem + (((t & 1) ^ 1) << 16);
    const int kn = (t + 1) << 7;
    const bool more = (t + 1) < NT;
    intx4 a[8], b[4];

    // ---- phase 0 (ks0, j01) ----
#pragma unroll
    for (int i = 0; i < 8; ++i) a[i] = rdA(bufc, 0, i);
    b[0] = rdB(bufc, 0, 0); b[1] = rdB(bufc, 0, 1);
    if (more) stage_plane(A, m0, K, kn, bufn, tid);
    SBAR();
    __builtin_amdgcn_s_setprio(1);
#pragma unroll
    for (int i = 0; i < 8; ++i) {
      acc[i][0] = __builtin_amdgcn_mfma_i32_16x16x64_i8(a[i], b[0], acc[i][0], 0, 0, 0);
      acc[i][1] = __builtin_amdgcn_mfma_i32_16x16x64_i8(a[i], b[1], acc[i][1], 0, 0, 0);
    }
    __builtin_amdgcn_s_setprio(0);
    SBAR();

    // ---- phase 1 (ks0, j23) ----
    b[2] = rdB(bufc, 0, 2); b[3] = rdB(bufc, 0, 3);
    if (more) stage_plane(B, n0, K, kn, bufn + 32768, tid);
    SBAR();
    __builtin_amdgcn_s_setprio(1);
#pragma unroll
    for (int i = 0; i < 8; ++i) {
      acc[i][2] = __builtin_amdgcn_mfma_i32_16x16x64_i8(a[i], b[2], acc[i][2], 0, 0, 0);
      acc[i][3] = __builtin_amdgcn_mfma_i32_16x16x64_i8(a[i], b[3], acc[i][3], 0, 0, 0);
    }
    __builtin_amdgcn_s_setprio(0);
    VMW(more);        // forces this tile's ks1 planes; leaves next ks0 in flight
    SBAR();

    // ---- phase 2 (ks1, j01) ----
#pragma unroll
    for (int i = 0; i < 8; ++i) a[i] = rdA(bufc, 1, i);
    b[0] = rdB(bufc, 1, 0); b[1] = rdB(bufc, 1, 1);
    if (more) stage_plane(A, m0, K, kn + 64, bufn + 16384, tid);
    SBAR();
    __builtin_amdgcn_s_setprio(1);
#pragma unroll
    for (int i = 0; i < 8; ++i) {
      acc[i][0] = __builtin_amdgcn_mfma_i32_16x16x64_i8(a[i], b[0], acc[i][0], 0, 0, 0);
      acc[i][1] = __builtin_amdgcn_mfma_i32_16x16x64_i8(a[i], b[1], acc[i][1], 0, 0, 0);
    }
    __builtin_amdgcn_s_setprio(0);
    SBAR();

    // ---- phase 3 (ks1, j23) ----
    b[2] = rdB(bufc, 1, 2); b[3] = rdB(bufc, 1, 3);
    if (more) stage_plane(B, n0, K, kn + 64, bufn + 49152, tid);
    SBAR();
    __builtin_amdgcn_s_setprio(1);
#pragma unroll
    for (int i = 0; i < 8; ++i) {
      acc[i][2] = __builtin_amdgcn_mfma_i32_16x16x64_i8(a[i], b[2], acc[i][2], 0, 0, 0);
      acc[i][3] = __builtin_amdgcn_mfma_i32_16x16x64_i8(a[i], b[3], acc[i][3], 0, 0, 0);
    }
    __builtin_amdgcn_s_setprio(0);
    VMW(more);        // forces next tile's ks0 planes; leaves next ks1 in flight
    SBAR();
  }

  // ---- epilogue: C/D layout col=lane&15, row=(lane>>4)*4+q (dtype-indep) ----
  float sbc[4];
#pragma unroll
  for (int j = 0; j < 4; ++j) sbc[j] = sB[n0 + (wc << 6) + (j << 4) + l15];
#pragma unroll
  for (int i = 0; i < 8; ++i) {
#pragma unroll
    for (int q = 0; q < 4; ++q) {
      const int row = m0 + (wr << 7) + (i << 4) + (slq << 2) + q;
      const float sa = sA[row];
      float* op = out + (size_t)row * N + n0 + (wc << 6) + l15;
#pragma unroll
      for (int j = 0; j < 4; ++j) {
        const float v = (float)acc[i][j][q] * sa * sbc[j];
        if (MODE == 1) {
          const float g = op[j << 4];                 // gate, written earlier
          op[j << 4] = g / (1.0f + expf(-g)) * v;     // silu(g) * u, in place
        } else {
          op[j << 4] = v;
        }
      }
    }
  }
}

// ---------------------------------------------------------------------------
extern "C" void kernel_launch(void* const* d_in, const int* in_sizes, int n_in,
                              void* d_out, int out_size, void* d_ws, size_t ws_size,
                              hipStream_t stream) {
  const float* x  = (const float*)d_in[0];
  const float* wg = (const float*)d_in[1];
  const float* wu = (const float*)d_in[2];
  const float* wd = (const float*)d_in[3];
  float* out = (float*)d_out;

  const int M = 8192, H = 2048, I = 6144;

  // 128 KiB dynamic LDS opt-in (idempotent; host-side, capture-safe)
  hipFuncSetAttribute((const void*)gemm8p_kernel<0>,
                      hipFuncAttributeMaxDynamicSharedMemorySize, 131072);
  hipFuncSetAttribute((const void*)gemm8p_kernel<1>,
                      hipFuncAttributeMaxDynamicSharedMemorySize, 131072);

  // ---- fixed workspace (~52.1 MiB) ----
  char* ws = (char*)d_ws;
  signed char* xq  = (signed char*)(ws);
  signed char* wgq = (signed char*)(ws + 16777216);
  signed char* wuq = (signed char*)(ws + 29360128);
  signed char* wdq = (signed char*)(ws + 41943040);
  float* sx  = (float*)(ws + 54525952);
  float* swg = (float*)(ws + 54558720);
  float* swu = (float*)(ws + 54583296);
  float* swd = (float*)(ws + 54607872);
  float* sh  = (float*)(ws + 54616064);
  const size_t chunk_base = 54648832;

  // ---- adaptive M-chunking (multiple of 256): h fp32 + hq i8 = 5B/elem ----
  size_t avail = (ws_size > chunk_base) ? (ws_size - chunk_base) : 0;
  long long c = (long long)(avail / ((size_t)I * 5));
  int CHUNK = (int)((c / 256) * 256);
  if (CHUNK > M) CHUNK = M;
  if (CHUNK < 256) CHUNK = 256;
  float* h = (float*)(ws + chunk_base);
  signed char* hq = (signed char*)(ws + chunk_base + (size_t)CHUNK * I * 4);

  // 1) fake-quant activations and weights -> i8 + fp32 scales
  quant_rows_i8_kernel<2><<<M, 256, 0, stream>>>(x,  xq,  sx,  H);
  quant_rows_i8_kernel<2><<<I, 256, 0, stream>>>(wg, wgq, swg, H);
  quant_rows_i8_kernel<2><<<I, 256, 0, stream>>>(wu, wuq, swu, H);
  quant_rows_i8_kernel<6><<<H, 256, 0, stream>>>(wd, wdq, swd, I);

  // 2) per chunk: gate GEMM -> g(=h); up GEMM reads g, writes silu(g)*u in
  //    place; quant h -> hq; down GEMM -> out. All grids are multiples of 8.
  for (int m0 = 0; m0 < M; m0 += CHUNK) {
    const int Mc = (M - m0 < CHUNK) ? (M - m0) : CHUNK;
    const int gTiles = Mc / 256;
    gemm8p_kernel<0><<<dim3(gTiles * (I / 256)), 512, 131072, stream>>>(
        xq + (size_t)m0 * H, wgq, sx + m0, swg, h, I, H);
    gemm8p_kernel<1><<<dim3(gTiles * (I / 256)), 512, 131072, stream>>>(
        xq + (size_t)m0 * H, wuq, sx + m0, swu, h, I, H);
    quant_rows_i8_kernel<6><<<Mc, 256, 0, stream>>>(h, hq, sh + m0, I);
    gemm8p_kernel<0><<<dim3(gTiles * (H / 256)), 512, 131072, stream>>>(
        hq, wdq, sh + m0, swd, out + (size_t)m0 * H, H, I);
  }
}

// Round 14
// 709.479 us; speedup vs baseline: 1.1159x; 1.1159x over previous
//
#include <hip/hip_runtime.h>
#include <hip/hip_bf16.h>
#include <math.h>

typedef __attribute__((ext_vector_type(4))) int intx4;    // 16 i8 (4 VGPR) / i32x4 acc

__device__ __forceinline__ void gload_lds16(const void* g, void* l) {
  __builtin_amdgcn_global_load_lds((__attribute__((address_space(1))) void*)g,
                                   (__attribute__((address_space(3))) void*)l,
                                   16, 0, 0);
}

__device__ __forceinline__ int pack4_i8(float a, float b, float c, float d) {
  return ((int)a & 255) | (((int)b & 255) << 8) | (((int)c & 255) << 16) | (((int)d & 255) << 24);
}

// ---------------------------------------------------------------------------
// Per-row symmetric int8 fake-quant, ONE WAVE PER ROW (4 rows / 256-thr block).
// No LDS, no barriers: lane-parallel absmax + wave shuffle-reduce, then packed
// i8 store. C = NV*256 floats per row (NV float4 per lane). Numerics identical
// to rounds 8-10 (rintf(v/scale), clamp, same EPS path).
// ---------------------------------------------------------------------------
template<int NV>
__global__ __launch_bounds__(256)
void quant_rows_w_kernel(const float* __restrict__ src,
                         signed char* __restrict__ dst,
                         float* __restrict__ scales,
                         int C) {
  const int lane = threadIdx.x & 63;
  const int row = (blockIdx.x << 2) + (threadIdx.x >> 6);
  const float4* s4 = (const float4*)(src + (size_t)row * C);
  float4 v[NV];
  float amax = 0.0f;
#pragma unroll
  for (int i = 0; i < NV; ++i) {
    v[i] = s4[lane + (i << 6)];
    amax = fmaxf(amax, fmaxf(fmaxf(fabsf(v[i].x), fabsf(v[i].y)),
                             fmaxf(fabsf(v[i].z), fabsf(v[i].w))));
  }
#pragma unroll
  for (int off = 32; off > 0; off >>= 1)
    amax = fmaxf(amax, __shfl_xor(amax, off));
  const float scale = fmaxf(amax * (1.0f / 127.0f), 1e-8f);
  if (lane == 0) scales[row] = scale;
  int* o4 = (int*)(dst + (size_t)row * C);
#pragma unroll
  for (int i = 0; i < NV; ++i) {
    const float q0 = fminf(fmaxf(rintf(v[i].x / scale), -127.0f), 127.0f);
    const float q1 = fminf(fmaxf(rintf(v[i].y / scale), -127.0f), 127.0f);
    const float q2 = fminf(fmaxf(rintf(v[i].z / scale), -127.0f), 127.0f);
    const float q3 = fminf(fmaxf(rintf(v[i].w / scale), -127.0f), 127.0f);
    o4[lane + (i << 6)] = pack4_i8(q0, q1, q2, q3);
  }
}

// ---------------------------------------------------------------------------
// i8 BT GEMM (round-9 kernel, verbatim — validated at 1418 TF dual):
// C[m,n] = (sum_k A[m,k]*B[n,k])_i32 * sA[m] * sB[n]
// 128x128 tile, BK=128, 4 waves (2x2), mfma_i32_16x16x64_i8,
// global_load_lds(16B) staging, both-sides XOR swizzle (conflict-free,
// measured 0). DUAL: two B share A staging; epilogue writes silu(g)*u fp32.
// ---------------------------------------------------------------------------
template<bool DUAL>
__global__ __launch_bounds__(256, 2)
void gemm_i8_kernel(const signed char* __restrict__ A,
                    const signed char* __restrict__ B0,
                    const signed char* __restrict__ B1,
                    const float* __restrict__ sA,
                    const float* __restrict__ sB0,
                    const float* __restrict__ sB1,
                    float* __restrict__ out,
                    int N, int K) {
  extern __shared__ __align__(16) char smem[];
  char* const As  = smem;            // 128 rows x 128B = 16 KB
  char* const Bs0 = smem + 16384;
  char* const Bs1 = smem + 32768;    // DUAL only

  const int nTn = N >> 7;
  const int nwg = gridDim.x;
  const int bid = blockIdx.x;
  const int cpx = nwg >> 3;          // grids are multiples of 8 -> bijective
  const int swz = (bid & 7) * cpx + (bid >> 3);
  const int tm = swz / nTn, tn = swz - tm * nTn;
  const int m0 = tm << 7, n0 = tn << 7;

  const int t = threadIdx.x;
  const int lane = t & 63;
  const int wid = t >> 6;
  const int wr = wid >> 1, wc = wid & 1;

  const intx4 zero = {0, 0, 0, 0};
  intx4 acc0[4][4];
  intx4 acc1[4][4];
#pragma unroll
  for (int i = 0; i < 4; ++i)
#pragma unroll
    for (int j = 0; j < 4; ++j) {
      acc0[i][j] = zero;
      if (DUAL) acc1[i][j] = zero;
    }

  for (int k0 = 0; k0 < K; k0 += 128) {
#pragma unroll
    for (int rr = 0; rr < 4; ++rr) {
      const int chunk = (rr << 8) + t;
      const int r = chunk >> 3;
      const int c8 = (chunk & 7) ^ (r & 7);
      gload_lds16(A + (size_t)(m0 + r) * K + (k0 + (c8 << 4)), As + (chunk << 4));
    }
#pragma unroll
    for (int rr = 0; rr < 4; ++rr) {
      const int chunk = (rr << 8) + t;
      const int r = chunk >> 3;
      const int c8 = (chunk & 7) ^ (r & 7);
      const size_t goff = (size_t)(n0 + r) * K + (k0 + (c8 << 4));
      gload_lds16(B0 + goff, Bs0 + (chunk << 4));
      if (DUAL) gload_lds16(B1 + goff, Bs1 + (chunk << 4));
    }
    __syncthreads();

#pragma unroll
    for (int ks = 0; ks < 2; ++ks) {   // two K=64 MFMA sub-steps per 128-K tile
      intx4 af[4], bf0[4], bf1[4];
#pragma unroll
      for (int i = 0; i < 4; ++i) {
        const int r = (wr << 6) + (i << 4) + (lane & 15);
        const int c8 = (ks << 2) + (lane >> 4);   // 16 consecutive i8 per lane
        af[i] = *(const intx4*)(As + r * 128 + ((c8 ^ (r & 7)) << 4));
      }
#pragma unroll
      for (int j = 0; j < 4; ++j) {
        const int r = (wc << 6) + (j << 4) + (lane & 15);
        const int c8 = (ks << 2) + (lane >> 4);
        const int off = r * 128 + ((c8 ^ (r & 7)) << 4);
        bf0[j] = *(const intx4*)(Bs0 + off);
        if (DUAL) bf1[j] = *(const intx4*)(Bs1 + off);
      }
#pragma unroll
      for (int i = 0; i < 4; ++i)
#pragma unroll
        for (int j = 0; j < 4; ++j) {
          acc0[i][j] = __builtin_amdgcn_mfma_i32_16x16x64_i8(af[i], bf0[j], acc0[i][j], 0, 0, 0);
          if (DUAL)
            acc1[i][j] = __builtin_amdgcn_mfma_i32_16x16x64_i8(af[i], bf1[j], acc1[i][j], 0, 0, 0);
        }
    }
    __syncthreads();
  }

  // Epilogue. C/D layout: col = lane&15, row = (lane>>4)*4 + q.
  float sb0c[4], sb1c[4];
#pragma unroll
  for (int j = 0; j < 4; ++j) {
    const int col = n0 + (wc << 6) + (j << 4) + (lane & 15);
    sb0c[j] = sB0[col];
    if (DUAL) sb1c[j] = sB1[col];
  }
#pragma unroll
  for (int i = 0; i < 4; ++i) {
#pragma unroll
    for (int q = 0; q < 4; ++q) {
      const int row = m0 + (wr << 6) + (i << 4) + ((lane >> 4) << 2) + q;
      const float sa = sA[row];
      float* op = out + (size_t)row * N + n0 + (wc << 6) + (lane & 15);
#pragma unroll
      for (int j = 0; j < 4; ++j) {
        const float g = (float)acc0[i][j][q] * sa * sb0c[j];
        if (DUAL) {
          const float u = (float)acc1[i][j][q] * sa * sb1c[j];
          op[j << 4] = g / (1.0f + expf(-g)) * u;   // silu(g) * u
        } else {
          op[j << 4] = g;
        }
      }
    }
  }
}

// ---------------------------------------------------------------------------
extern "C" void kernel_launch(void* const* d_in, const int* in_sizes, int n_in,
                              void* d_out, int out_size, void* d_ws, size_t ws_size,
                              hipStream_t stream) {
  const float* x  = (const float*)d_in[0];   // [4,2048,2048]
  const float* wg = (const float*)d_in[1];   // [6144,2048]
  const float* wu = (const float*)d_in[2];   // [6144,2048]
  const float* wd = (const float*)d_in[3];   // [2048,6144]
  float* out = (float*)d_out;                // [4,2048,2048] fp32

  const int M = 8192, H = 2048, I = 6144;

  // ---- fixed workspace (~52.1 MiB) ----
  char* ws = (char*)d_ws;
  signed char* xq  = (signed char*)(ws);                  // M*H
  signed char* wgq = (signed char*)(ws + 16777216);       // I*H
  signed char* wuq = (signed char*)(ws + 29360128);
  signed char* wdq = (signed char*)(ws + 41943040);
  float* sx  = (float*)(ws + 54525952);
  float* swg = (float*)(ws + 54558720);
  float* swu = (float*)(ws + 54583296);
  float* swd = (float*)(ws + 54607872);
  float* sh  = (float*)(ws + 54616064);
  const size_t chunk_base = 54648832;

  // ---- adaptive M-chunking: per-row cost = I*4 (h fp32) + I*1 (hq i8) ----
  size_t avail = (ws_size > chunk_base) ? (ws_size - chunk_base) : 0;
  long long c = (long long)(avail / ((size_t)I * 5));
  int CHUNK = (int)((c / 128) * 128);
  if (CHUNK > M) CHUNK = M;
  if (CHUNK < 128) CHUNK = 128;
  float* h = (float*)(ws + chunk_base);
  signed char* hq = (signed char*)(ws + chunk_base + (size_t)CHUNK * I * 4);

  // 1) fake-quant activations and weights -> i8 + fp32 scales (wave-per-row)
  quant_rows_w_kernel<8> <<<M / 4, 256, 0, stream>>>(x,  xq,  sx,  H);
  quant_rows_w_kernel<8> <<<I / 4, 256, 0, stream>>>(wg, wgq, swg, H);
  quant_rows_w_kernel<8> <<<I / 4, 256, 0, stream>>>(wu, wuq, swu, H);
  quant_rows_w_kernel<24><<<H / 4, 256, 0, stream>>>(wd, wdq, swd, I);

  // 2) per M-chunk: fused gate+up i8 GEMM -> h (fp32), quantize h, down GEMM
  for (int m0 = 0; m0 < M; m0 += CHUNK) {
    const int Mc = (M - m0 < CHUNK) ? (M - m0) : CHUNK;
    gemm_i8_kernel<true><<<dim3((Mc / 128) * (I / 128)), 256, 49152, stream>>>(
        xq + (size_t)m0 * H, wgq, wuq, sx + m0, swg, swu, h, I, H);
    quant_rows_w_kernel<24><<<Mc / 4, 256, 0, stream>>>(h, hq, sh + m0, I);
    gemm_i8_kernel<false><<<dim3((Mc / 128) * (H / 128)), 256, 32768, stream>>>(
        hq, wdq, nullptr, sh + m0, swd, nullptr, out + (size_t)m0 * H, H, I);
  }
}

// Round 16
// 665.507 us; speedup vs baseline: 1.1896x; 1.0661x over previous
//
#include <hip/hip_runtime.h>
#include <hip/hip_bf16.h>
#include <math.h>

typedef __attribute__((ext_vector_type(4))) int intx4;    // 16 i8 (4 VGPR) / i32x4 acc

__device__ __forceinline__ void gload_lds16(const void* g, void* l) {
  __builtin_amdgcn_global_load_lds((__attribute__((address_space(1))) void*)g,
                                   (__attribute__((address_space(3))) void*)l,
                                   16, 0, 0);
}

__device__ __forceinline__ int pack4_i8(float a, float b, float c, float d) {
  return ((int)a & 255) | (((int)b & 255) << 8) | (((int)c & 255) << 16) | (((int)d & 255) << 24);
}

// ---------------------------------------------------------------------------
// Per-row symmetric int8 fake-quant, one wave per row (neutral vs round-9
// version, kept for fewer dispatches). Numerics identical to rounds 8-14.
// ---------------------------------------------------------------------------
template<int NV>
__global__ __launch_bounds__(256)
void quant_rows_w_kernel(const float* __restrict__ src,
                         signed char* __restrict__ dst,
                         float* __restrict__ scales,
                         int C) {
  const int lane = threadIdx.x & 63;
  const int row = (blockIdx.x << 2) + (threadIdx.x >> 6);
  const float4* s4 = (const float4*)(src + (size_t)row * C);
  float4 v[NV];
  float amax = 0.0f;
#pragma unroll
  for (int i = 0; i < NV; ++i) {
    v[i] = s4[lane + (i << 6)];
    amax = fmaxf(amax, fmaxf(fmaxf(fabsf(v[i].x), fabsf(v[i].y)),
                             fmaxf(fabsf(v[i].z), fabsf(v[i].w))));
  }
#pragma unroll
  for (int off = 32; off > 0; off >>= 1)
    amax = fmaxf(amax, __shfl_xor(amax, off));
  const float scale = fmaxf(amax * (1.0f / 127.0f), 1e-8f);
  if (lane == 0) scales[row] = scale;
  int* o4 = (int*)(dst + (size_t)row * C);
#pragma unroll
  for (int i = 0; i < NV; ++i) {
    const float q0 = fminf(fmaxf(rintf(v[i].x / scale), -127.0f), 127.0f);
    const float q1 = fminf(fmaxf(rintf(v[i].y / scale), -127.0f), 127.0f);
    const float q2 = fminf(fmaxf(rintf(v[i].z / scale), -127.0f), 127.0f);
    const float q3 = fminf(fmaxf(rintf(v[i].w / scale), -127.0f), 127.0f);
    o4[lane + (i << 6)] = pack4_i8(q0, q1, q2, q3);
  }
}

// ---------------------------------------------------------------------------
// i8 BT GEMM (round-9 compute structure verbatim; ONLY the tile-order swizzle
// changed): C[m,n] = (sum_k A[m,k]*B[n,k])_i32 * sA[m] * sB[n]
// 128x128 tile, BK=128, 4 waves, mfma_i32_16x16x64_i8, gload_lds staging,
// both-sides XOR swizzle (measured 0 conflicts).
//
// Tile order: after the bijective XCD transform, tiles are walked in BANDS
// of 8 N-tiles (tn fast within band, tm slow). An XCD's ~64 concurrent
// blocks then cover an ~8x8 supertile: B-band (4 MB dual) stays L2-resident,
// A panels get 8x reuse, full A+B (64 MB) goes L3-resident. Attacks the
// measured 620 MB/dispatch HBM over-fetch (10x unique inputs, round-14 PMC).
// Requires nTn % 8 == 0 (48 and 16 here). Bijective for all launched shapes
// (verified: dual 3072=64x48, down 1024=64x16, and chunk tails).
// ---------------------------------------------------------------------------
template<bool DUAL>
__global__ __launch_bounds__(256, 2)
void gemm_i8_kernel(const signed char* __restrict__ A,
                    const signed char* __restrict__ B0,
                    const signed char* __restrict__ B1,
                    const float* __restrict__ sA,
                    const float* __restrict__ sB0,
                    const float* __restrict__ sB1,
                    float* __restrict__ out,
                    int N, int K) {
  extern __shared__ __align__(16) char smem[];
  char* const As  = smem;            // 128 rows x 128B = 16 KB
  char* const Bs0 = smem + 16384;
  char* const Bs1 = smem + 32768;    // DUAL only

  const int nTn = N >> 7;
  const int nwg = gridDim.x;
  const int bid = blockIdx.x;
  const int cpx = nwg >> 3;          // grids are multiples of 8 -> bijective
  const int swz = (bid & 7) * cpx + (bid >> 3);
  // band decomposition (bijective: swz -> (band, tm, tn))
  const int nTm = nwg / nTn;
  const int band = swz / (nTm << 3);
  const int idx  = swz - band * (nTm << 3);
  const int tm = idx >> 3;
  const int tn = (band << 3) + (idx & 7);
  const int m0 = tm << 7, n0 = tn << 7;

  const int t = threadIdx.x;
  const int lane = t & 63;
  const int wid = t >> 6;
  const int wr = wid >> 1, wc = wid & 1;

  const intx4 zero = {0, 0, 0, 0};
  intx4 acc0[4][4];
  intx4 acc1[4][4];
#pragma unroll
  for (int i = 0; i < 4; ++i)
#pragma unroll
    for (int j = 0; j < 4; ++j) {
      acc0[i][j] = zero;
      if (DUAL) acc1[i][j] = zero;
    }

  for (int k0 = 0; k0 < K; k0 += 128) {
#pragma unroll
    for (int rr = 0; rr < 4; ++rr) {
      const int chunk = (rr << 8) + t;
      const int r = chunk >> 3;
      const int c8 = (chunk & 7) ^ (r & 7);
      gload_lds16(A + (size_t)(m0 + r) * K + (k0 + (c8 << 4)), As + (chunk << 4));
    }
#pragma unroll
    for (int rr = 0; rr < 4; ++rr) {
      const int chunk = (rr << 8) + t;
      const int r = chunk >> 3;
      const int c8 = (chunk & 7) ^ (r & 7);
      const size_t goff = (size_t)(n0 + r) * K + (k0 + (c8 << 4));
      gload_lds16(B0 + goff, Bs0 + (chunk << 4));
      if (DUAL) gload_lds16(B1 + goff, Bs1 + (chunk << 4));
    }
    __syncthreads();

#pragma unroll
    for (int ks = 0; ks < 2; ++ks) {   // two K=64 MFMA sub-steps per 128-K tile
      intx4 af[4], bf0[4], bf1[4];
#pragma unroll
      for (int i = 0; i < 4; ++i) {
        const int r = (wr << 6) + (i << 4) + (lane & 15);
        const int c8 = (ks << 2) + (lane >> 4);   // 16 consecutive i8 per lane
        af[i] = *(const intx4*)(As + r * 128 + ((c8 ^ (r & 7)) << 4));
      }
#pragma unroll
      for (int j = 0; j < 4; ++j) {
        const int r = (wc << 6) + (j << 4) + (lane & 15);
        const int c8 = (ks << 2) + (lane >> 4);
        const int off = r * 128 + ((c8 ^ (r & 7)) << 4);
        bf0[j] = *(const intx4*)(Bs0 + off);
        if (DUAL) bf1[j] = *(const intx4*)(Bs1 + off);
      }
#pragma unroll
      for (int i = 0; i < 4; ++i)
#pragma unroll
        for (int j = 0; j < 4; ++j) {
          acc0[i][j] = __builtin_amdgcn_mfma_i32_16x16x64_i8(af[i], bf0[j], acc0[i][j], 0, 0, 0);
          if (DUAL)
            acc1[i][j] = __builtin_amdgcn_mfma_i32_16x16x64_i8(af[i], bf1[j], acc1[i][j], 0, 0, 0);
        }
    }
    __syncthreads();
  }

  // Epilogue. C/D layout: col = lane&15, row = (lane>>4)*4 + q.
  float sb0c[4], sb1c[4];
#pragma unroll
  for (int j = 0; j < 4; ++j) {
    const int col = n0 + (wc << 6) + (j << 4) + (lane & 15);
    sb0c[j] = sB0[col];
    if (DUAL) sb1c[j] = sB1[col];
  }
#pragma unroll
  for (int i = 0; i < 4; ++i) {
#pragma unroll
    for (int q = 0; q < 4; ++q) {
      const int row = m0 + (wr << 6) + (i << 4) + ((lane >> 4) << 2) + q;
      const float sa = sA[row];
      float* op = out + (size_t)row * N + n0 + (wc << 6) + (lane & 15);
#pragma unroll
      for (int j = 0; j < 4; ++j) {
        const float g = (float)acc0[i][j][q] * sa * sb0c[j];
        if (DUAL) {
          const float u = (float)acc1[i][j][q] * sa * sb1c[j];
          op[j << 4] = g / (1.0f + expf(-g)) * u;   // silu(g) * u
        } else {
          op[j << 4] = g;
        }
      }
    }
  }
}

// ---------------------------------------------------------------------------
extern "C" void kernel_launch(void* const* d_in, const int* in_sizes, int n_in,
                              void* d_out, int out_size, void* d_ws, size_t ws_size,
                              hipStream_t stream) {
  const float* x  = (const float*)d_in[0];   // [4,2048,2048]
  const float* wg = (const float*)d_in[1];   // [6144,2048]
  const float* wu = (const float*)d_in[2];   // [6144,2048]
  const float* wd = (const float*)d_in[3];   // [2048,6144]
  float* out = (float*)d_out;                // [4,2048,2048] fp32

  const int M = 8192, H = 2048, I = 6144;

  // ---- fixed workspace (~52.1 MiB) ----
  char* ws = (char*)d_ws;
  signed char* xq  = (signed char*)(ws);                  // M*H
  signed char* wgq = (signed char*)(ws + 16777216);       // I*H
  signed char* wuq = (signed char*)(ws + 29360128);
  signed char* wdq = (signed char*)(ws + 41943040);
  float* sx  = (float*)(ws + 54525952);
  float* swg = (float*)(ws + 54558720);
  float* swu = (float*)(ws + 54583296);
  float* swd = (float*)(ws + 54607872);
  float* sh  = (float*)(ws + 54616064);
  const size_t chunk_base = 54648832;

  // ---- adaptive M-chunking: per-row cost = I*4 (h fp32) + I*1 (hq i8) ----
  size_t avail = (ws_size > chunk_base) ? (ws_size - chunk_base) : 0;
  long long c = (long long)(avail / ((size_t)I * 5));
  int CHUNK = (int)((c / 128) * 128);
  if (CHUNK > M) CHUNK = M;
  if (CHUNK < 128) CHUNK = 128;
  float* h = (float*)(ws + chunk_base);
  signed char* hq = (signed char*)(ws + chunk_base + (size_t)CHUNK * I * 4);

  // 1) fake-quant activations and weights -> i8 + fp32 scales (wave-per-row)
  quant_rows_w_kernel<8> <<<M / 4, 256, 0, stream>>>(x,  xq,  sx,  H);
  quant_rows_w_kernel<8> <<<I / 4, 256, 0, stream>>>(wg, wgq, swg, H);
  quant_rows_w_kernel<8> <<<I / 4, 256, 0, stream>>>(wu, wuq, swu, H);
  quant_rows_w_kernel<24><<<H / 4, 256, 0, stream>>>(wd, wdq, swd, I);

  // 2) per M-chunk: fused gate+up i8 GEMM -> h (fp32), quantize h, down GEMM
  for (int m0 = 0; m0 < M; m0 += CHUNK) {
    const int Mc = (M - m0 < CHUNK) ? (M - m0) : CHUNK;
    gemm_i8_kernel<true><<<dim3((Mc / 128) * (I / 128)), 256, 49152, stream>>>(
        xq + (size_t)m0 * H, wgq, wuq, sx + m0, swg, swu, h, I, H);
    quant_rows_w_kernel<24><<<Mc / 4, 256, 0, stream>>>(h, hq, sh + m0, I);
    gemm_i8_kernel<false><<<dim3((Mc / 128) * (H / 128)), 256, 32768, stream>>>(
        hq, wdq, nullptr, sh + m0, swd, nullptr, out + (size_t)m0 * H, H, I);
  }
}